// Round 1
// baseline (1655.643 us; speedup 1.0000x reference)
//
#include <hip/hip_runtime.h>
#include <hip/hip_bf16.h>
#include <cstdint>
#include <cstddef>

#define B_    8
#define S_    2048
#define D_    1024
#define DFF_  4096
#define E1_   8
#define E2_   16
#define T_    (B_*S_)
#define CAP1_ 2560
#define CAP2_ 1280

typedef __bf16 bf16x8 __attribute__((ext_vector_type(8)));
typedef float  f32x4  __attribute__((ext_vector_type(4)));

__device__ __forceinline__ unsigned short f2bf(float x) {
  return __builtin_bit_cast(unsigned short, (__bf16)x);
}

// ---------------- gating: logits = X @ WG, softmax-max + argmax ----------------
template<int E>
__global__ __launch_bounds__(256)
void gate_kernel(const float* __restrict__ X, const float* __restrict__ WG,
                 int* __restrict__ idxO, float* __restrict__ gateO) {
  const int lane = threadIdx.x & 63;
  const int wv   = threadIdx.x >> 6;
  const int t    = blockIdx.x * 4 + wv;
  const float* xr = X + (size_t)t * D_;
  float acc[E];
#pragma unroll
  for (int e = 0; e < E; ++e) acc[e] = 0.f;
#pragma unroll
  for (int i = 0; i < 4; ++i) {
    float4 xv = *(const float4*)(xr + i * 256 + lane * 4);
    int kb = i * 256 + lane * 4;
#pragma unroll
    for (int j = 0; j < 4; ++j) {
      float xs = (&xv.x)[j];
      const float* wr = WG + (size_t)(kb + j) * E;
#pragma unroll
      for (int e = 0; e < E; ++e) acc[e] += xs * wr[e];
    }
  }
#pragma unroll
  for (int e = 0; e < E; ++e) {
    float v = acc[e];
#pragma unroll
    for (int s = 32; s >= 1; s >>= 1) v += __shfl_xor(v, s, 64);
    acc[e] = v;
  }
  if (lane == 0) {
    float mx = acc[0]; int mi = 0;
#pragma unroll
    for (int e = 1; e < E; ++e) if (acc[e] > mx) { mx = acc[e]; mi = e; }
    float s = 0.f;
#pragma unroll
    for (int e = 0; e < E; ++e) s += expf(acc[e] - mx);
    idxO[t]  = mi;
    gateO[t] = 1.0f / s;   // max softmax prob
  }
}

// ---------------- order-preserving per-expert position scan ----------------
__global__ __launch_bounds__(1024)
void scan_kernel(const int* __restrict__ idx, int E, int cap,
                 int* __restrict__ pos, int* __restrict__ kept) {
  __shared__ int cnt[16][17];
  __shared__ int gbase[16];
  const int tid = threadIdx.x;
  const int w = tid >> 6, lane = tid & 63;
  if (tid < E) gbase[tid] = 0;
  __syncthreads();
  const unsigned long long lt = (lane == 63) ? 0xFFFFFFFFFFFFFFFFull >> 1
                                             : ((1ull << lane) - 1ull);
  for (int it = 0; it < T_ / 1024; ++it) {
    int t = it * 1024 + tid;
    int mi = idx[t];
    int rank = 0;
    for (int e = 0; e < E; ++e) {
      unsigned long long m = __ballot(mi == e);
      if (lane == 0) cnt[w][e] = __popcll(m);
      if (mi == e) rank = __popcll(m & lt);
    }
    __syncthreads();
    int off = 0;
    for (int w2 = 0; w2 < w; ++w2) off += cnt[w2][mi];
    pos[t] = gbase[mi] + off + rank;
    __syncthreads();
    if (tid < E) {
      int tot = 0;
      for (int w2 = 0; w2 < 16; ++w2) tot += cnt[w2][tid];
      gbase[tid] += tot;
    }
    __syncthreads();
  }
  if (tid < E) kept[tid] = min(gbase[tid], cap);
}

// ---------------- scatter tokens to expert buffers (f32 -> bf16) ----------------
__global__ __launch_bounds__(64)
void scatter_kernel(const float* __restrict__ X, const int* __restrict__ idx,
                    const int* __restrict__ pos, int cap,
                    unsigned short* __restrict__ xbuf, int* __restrict__ tokmap,
                    float* __restrict__ mzero) {
  const int t = blockIdx.x;
  const int lane = threadIdx.x;
  const int p = pos[t];
  if (p < cap) {
    const size_t dst = ((size_t)idx[t] * cap + p) * D_;
    const float* xr = X + (size_t)t * D_;
#pragma unroll
    for (int i = 0; i < 4; ++i) {
      float4 v = *(const float4*)(xr + i * 256 + lane * 4);
      ushort4 o;
      o.x = f2bf(v.x); o.y = f2bf(v.y); o.z = f2bf(v.z); o.w = f2bf(v.w);
      *(ushort4*)(xbuf + dst + i * 256 + lane * 4) = o;
    }
    if (lane == 0) tokmap[(size_t)idx[t] * cap + p] = t;
  } else {
    float4 z = {0.f, 0.f, 0.f, 0.f};
    float* mr = mzero + (size_t)t * D_;
#pragma unroll
    for (int i = 0; i < 4; ++i) *(float4*)(mr + i * 256 + lane * 4) = z;
  }
}

// ---------------- expert GEMM: C = A(bf16) * Bw(f32->bf16) + bias ----------------
// MODE 0: Hout = relu(C) as bf16.   MODE 1: Mout[tok] = C * gate[tok] (gather).
template<int MODE>
__global__ __launch_bounds__(256)
void moe_gemm(const unsigned short* __restrict__ A, const float* __restrict__ Bw,
              const float* __restrict__ bias, int K, int N, int cap,
              const int* __restrict__ kept,
              unsigned short* __restrict__ Hout, float* __restrict__ Mout,
              const int* __restrict__ tokmap, const float* __restrict__ gate) {
  __shared__ char smem[16384];
  char* As = smem;          // [128][32] bf16, row-major, XOR-swizzled
  char* Bs = smem + 8192;   // [128n][32k] bf16, n-major, XOR-swizzled
  const int tid  = threadIdx.x;
  const int lane = tid & 63;
  const int wv   = tid >> 6;
  const int wr   = wv >> 1, wc = wv & 1;
  const int nb = blockIdx.x, mb = blockIdx.y;
  const int e  = (mb * 128) / cap;
  const int r0 = mb * 128 - e * cap;
  const int kept_e = kept[e];
  if (r0 >= kept_e) return;
  const float* Be = Bw + (size_t)e * K * N + (size_t)nb * 128;

  f32x4 acc[4][4];
#pragma unroll
  for (int m = 0; m < 4; ++m)
#pragma unroll
    for (int n = 0; n < 4; ++n) acc[m][n] = (f32x4){0.f, 0.f, 0.f, 0.f};

  const int bn  = tid & 127;   // B-stage: column within tile
  const int bkh = tid >> 7;    // 0/1

  for (int k0 = 0; k0 < K; k0 += 32) {
    // A tile: global_load_lds, linear LDS dest, source pre-swizzled
#pragma unroll
    for (int p = 0; p < 2; ++p) {
      int row = (p * 256 + tid) >> 2;
      int cb  = (tid & 3) * 16;
      int scb = cb ^ ((row & 3) << 4);
      const unsigned short* g = A + (size_t)(mb * 128 + row) * K + k0 + (scb >> 1);
      char* l = As + (size_t)(p * 256 + (tid & ~63)) * 16;
      __builtin_amdgcn_global_load_lds((const __attribute__((address_space(1))) void*)g,
                                       (__attribute__((address_space(3))) void*)l,
                                       16, 0, 0);
    }
    // B tile: reg-stage f32 -> bf16, transpose to [n][k], swizzled
#pragma unroll
    for (int h2 = 0; h2 < 2; ++h2) {
      int ks = h2 * 16 + bkh * 8;
      uint4 pack;
      unsigned short* ps = (unsigned short*)&pack;
#pragma unroll
      for (int j = 0; j < 8; ++j)
        ps[j] = f2bf(Be[(size_t)(k0 + ks + j) * N + bn]);
      int boff = bn * 64 + ((ks * 2) ^ ((bn & 3) << 4));
      *(uint4*)(Bs + boff) = pack;
    }
    __syncthreads();

    bf16x8 af[4], bfr[4];
    const int g16 = (lane >> 4) * 16;
    const int r16 = lane & 15;
#pragma unroll
    for (int m = 0; m < 4; ++m) {
      int row = wr * 64 + m * 16 + r16;
      af[m] = *(const bf16x8*)(As + row * 64 + (g16 ^ ((row & 3) << 4)));
    }
#pragma unroll
    for (int n = 0; n < 4; ++n) {
      int col = wc * 64 + n * 16 + r16;
      bfr[n] = *(const bf16x8*)(Bs + col * 64 + (g16 ^ ((col & 3) << 4)));
    }
#pragma unroll
    for (int m = 0; m < 4; ++m)
#pragma unroll
      for (int n = 0; n < 4; ++n)
        acc[m][n] = __builtin_amdgcn_mfma_f32_16x16x32_bf16(af[m], bfr[n], acc[m][n], 0, 0, 0);
    __syncthreads();
  }

  // epilogue
  const int r16 = lane & 15, rg = lane >> 4;
  float bv[4];
#pragma unroll
  for (int n = 0; n < 4; ++n)
    bv[n] = bias[(size_t)e * N + nb * 128 + wc * 64 + n * 16 + r16];

#pragma unroll
  for (int m = 0; m < 4; ++m) {
#pragma unroll
    for (int r = 0; r < 4; ++r) {
      const int lrow = wr * 64 + m * 16 + rg * 4 + r;
      if (MODE == 0) {
        unsigned short* orow = Hout + (size_t)(mb * 128 + lrow) * N + nb * 128;
#pragma unroll
        for (int n = 0; n < 4; ++n) {
          float v = acc[m][n][r] + bv[n];
          orow[wc * 64 + n * 16 + r16] = f2bf(fmaxf(v, 0.f));
        }
      } else {
        const int lr = r0 + lrow;
        if (lr < kept_e) {
          const int tok = tokmap[mb * 128 + lrow];
          const float gsc = gate[tok];
          float* orow = Mout + (size_t)tok * N + nb * 128;
#pragma unroll
          for (int n = 0; n < 4; ++n)
            orow[wc * 64 + n * 16 + r16] = (acc[m][n][r] + bv[n]) * gsc;
        }
      }
    }
  }
}

// ---------------- residual + mean over S ----------------
__global__ __launch_bounds__(256)
void reduce_kernel(const float* __restrict__ X, const float* __restrict__ M2,
                   float* __restrict__ sent) {
  const int c = blockIdx.x * 256 + threadIdx.x;   // 0..1023
  const int b = blockIdx.z;
  const int s0 = blockIdx.y * 128;
  float a = 0.f;
  size_t base = ((size_t)b * S_ + s0) * D_ + c;
  for (int s = 0; s < 128; ++s) a += X[base + (size_t)s * D_] + M2[base + (size_t)s * D_];
  atomicAdd(&sent[b * D_ + c], a * (1.0f / (float)S_));
}

// ---------------- logsumexp NLL loss ----------------
__global__ __launch_bounds__(64)
void loss_kernel(const float* __restrict__ sent, const int* __restrict__ y,
                 float* __restrict__ out) {
  const int lane = threadIdx.x;
  float total = 0.f;
  for (int b = 0; b < B_; ++b) {
    const float* s = sent + b * D_;
    float v[16];
    float mx = -1e30f;
#pragma unroll
    for (int i = 0; i < 16; ++i) { v[i] = s[lane + i * 64]; mx = fmaxf(mx, v[i]); }
#pragma unroll
    for (int sh = 32; sh >= 1; sh >>= 1) mx = fmaxf(mx, __shfl_xor(mx, sh, 64));
    float sm = 0.f;
#pragma unroll
    for (int i = 0; i < 16; ++i) sm += expf(v[i] - mx);
#pragma unroll
    for (int sh = 32; sh >= 1; sh >>= 1) sm += __shfl_xor(sm, sh, 64);
    total += logf(sm) + mx - s[y[b]];
  }
  if (lane == 0) out[0] = total * (1.0f / (float)B_);
}

extern "C" void kernel_launch(void* const* d_in, const int* in_sizes, int n_in,
                              void* d_out, int out_size, void* d_ws, size_t ws_size,
                              hipStream_t stream) {
  const float* x   = (const float*)d_in[0];
  const int*   y   = (const int*)d_in[1];
  const float* wg1 = (const float*)d_in[2];
  const float* w1a = (const float*)d_in[3];
  const float* b1a = (const float*)d_in[4];
  const float* w2a = (const float*)d_in[5];
  const float* b2a = (const float*)d_in[6];
  const float* wg2 = (const float*)d_in[7];
  const float* w1b = (const float*)d_in[8];
  const float* b1b = (const float*)d_in[9];
  const float* w2b = (const float*)d_in[10];
  const float* b2b = (const float*)d_in[11];
  float* out = (float*)d_out;
  (void)in_sizes; (void)n_in; (void)out_size; (void)ws_size;

  char* base = (char*)d_ws;
  size_t o = 0;
  auto alloc = [&](size_t bytes) { size_t r = o; o = (o + bytes + 255) & ~(size_t)255; return r; };
  int*   idx1    = (int*)  (base + alloc((size_t)T_ * 4));
  int*   pos1    = (int*)  (base + alloc((size_t)T_ * 4));
  float* gate1   = (float*)(base + alloc((size_t)T_ * 4));
  int*   idx2    = (int*)  (base + alloc((size_t)T_ * 4));
  int*   pos2    = (int*)  (base + alloc((size_t)T_ * 4));
  float* gate2   = (float*)(base + alloc((size_t)T_ * 4));
  int*   kept1   = (int*)  (base + alloc(64 * 4));
  int*   kept2   = (int*)  (base + alloc(64 * 4));
  int*   tokmap1 = (int*)  (base + alloc((size_t)E1_ * CAP1_ * 4));
  int*   tokmap2 = (int*)  (base + alloc((size_t)E2_ * CAP2_ * 4));
  float* sent    = (float*)(base + alloc((size_t)B_ * D_ * 4));
  float* m1      = (float*)(base + alloc((size_t)T_ * D_ * 4));
  float* m2      = (float*)(base + alloc((size_t)T_ * D_ * 4));
  unsigned short* xbuf = (unsigned short*)(base + alloc((size_t)E1_ * CAP1_ * D_ * 2));
  unsigned short* h    = (unsigned short*)(base + alloc((size_t)E1_ * CAP1_ * DFF_ * 2));

  hipMemsetAsync(sent, 0, (size_t)B_ * D_ * 4, stream);

  // ----- layer 1 (E=8, cap=2560) -----
  gate_kernel<E1_><<<T_ / 4, 256, 0, stream>>>(x, wg1, idx1, gate1);
  scan_kernel<<<1, 1024, 0, stream>>>(idx1, E1_, CAP1_, pos1, kept1);
  scatter_kernel<<<T_, 64, 0, stream>>>(x, idx1, pos1, CAP1_, xbuf, tokmap1, m1);
  moe_gemm<0><<<dim3(DFF_ / 128, (E1_ * CAP1_) / 128), 256, 0, stream>>>(
      xbuf, w1a, b1a, D_, DFF_, CAP1_, kept1, h, nullptr, nullptr, nullptr);
  moe_gemm<1><<<dim3(D_ / 128, (E1_ * CAP1_) / 128), 256, 0, stream>>>(
      h, w2a, b2a, DFF_, D_, CAP1_, kept1, nullptr, m1, tokmap1, gate1);

  // ----- layer 2 (E=16, cap=1280) -----
  gate_kernel<E2_><<<T_ / 4, 256, 0, stream>>>(m1, wg2, idx2, gate2);
  scan_kernel<<<1, 1024, 0, stream>>>(idx2, E2_, CAP2_, pos2, kept2);
  scatter_kernel<<<T_, 64, 0, stream>>>(m1, idx2, pos2, CAP2_, xbuf, tokmap2, m2);
  moe_gemm<0><<<dim3(DFF_ / 128, (E2_ * CAP2_) / 128), 256, 0, stream>>>(
      xbuf, w1b, b1b, D_, DFF_, CAP2_, kept2, h, nullptr, nullptr, nullptr);
  moe_gemm<1><<<dim3(D_ / 128, (E2_ * CAP2_) / 128), 256, 0, stream>>>(
      h, w2b, b2b, DFF_, D_, CAP2_, kept2, nullptr, m2, tokmap2, gate2);

  // ----- residual + mean + loss -----
  reduce_kernel<<<dim3(D_ / 256, S_ / 128, B_), 256, 0, stream>>>(x, m2, sent);
  loss_kernel<<<1, 64, 0, stream>>>(sent, y, out);
}

// Round 3
// 1542.163 us; speedup vs baseline: 1.0736x; 1.0736x over previous
//
#include <hip/hip_runtime.h>
#include <hip/hip_bf16.h>
#include <cstdint>
#include <cstddef>

#define B_    8
#define S_    2048
#define D_    1024
#define DFF_  4096
#define E1_   8
#define E2_   16
#define T_    (B_*S_)
#define CAP1_ 2560
#define CAP2_ 1280
#define EC_   20480   // E1_*CAP1_ == E2_*CAP2_ == padded expert-buffer rows

typedef __bf16 bf16x8 __attribute__((ext_vector_type(8)));
typedef float  f32x4  __attribute__((ext_vector_type(4)));

__device__ __forceinline__ unsigned short f2bf(float x) {
  return __builtin_bit_cast(unsigned short, (__bf16)x);
}

// ---------------- gating: logits = X @ WG, softmax-max + argmax ----------------
template<int E>
__global__ __launch_bounds__(256)
void gate_kernel(const float* __restrict__ X, const float* __restrict__ WG,
                 int* __restrict__ idxO, float* __restrict__ gateO) {
  const int lane = threadIdx.x & 63;
  const int wv   = threadIdx.x >> 6;
  const int t    = blockIdx.x * 4 + wv;
  const float* xr = X + (size_t)t * D_;
  float acc[E];
#pragma unroll
  for (int e = 0; e < E; ++e) acc[e] = 0.f;
#pragma unroll
  for (int i = 0; i < 4; ++i) {
    float4 xv = *(const float4*)(xr + i * 256 + lane * 4);
    int kb = i * 256 + lane * 4;
#pragma unroll
    for (int j = 0; j < 4; ++j) {
      float xs = (&xv.x)[j];
      const float* wr = WG + (size_t)(kb + j) * E;
#pragma unroll
      for (int e = 0; e < E; ++e) acc[e] += xs * wr[e];
    }
  }
#pragma unroll
  for (int e = 0; e < E; ++e) {
    float v = acc[e];
#pragma unroll
    for (int s = 32; s >= 1; s >>= 1) v += __shfl_xor(v, s, 64);
    acc[e] = v;
  }
  if (lane == 0) {
    float mx = acc[0]; int mi = 0;
#pragma unroll
    for (int e = 1; e < E; ++e) if (acc[e] > mx) { mx = acc[e]; mi = e; }
    float s = 0.f;
#pragma unroll
    for (int e = 0; e < E; ++e) s += expf(acc[e] - mx);
    idxO[t]  = mi;
    gateO[t] = 1.0f / s;   // max softmax prob
  }
}

// ---------------- order-preserving per-expert position scan ----------------
__global__ __launch_bounds__(1024)
void scan_kernel(const int* __restrict__ idx, int E, int cap,
                 int* __restrict__ pos, int* __restrict__ kept) {
  __shared__ int cnt[16][17];
  __shared__ int gbase[16];
  const int tid = threadIdx.x;
  const int w = tid >> 6, lane = tid & 63;
  if (tid < E) gbase[tid] = 0;
  __syncthreads();
  const unsigned long long lt = (lane == 63) ? 0xFFFFFFFFFFFFFFFFull >> 1
                                             : ((1ull << lane) - 1ull);
  for (int it = 0; it < T_ / 1024; ++it) {
    int t = it * 1024 + tid;
    int mi = idx[t];
    int rank = 0;
    for (int e = 0; e < E; ++e) {
      unsigned long long m = __ballot(mi == e);
      if (lane == 0) cnt[w][e] = __popcll(m);
      if (mi == e) rank = __popcll(m & lt);
    }
    __syncthreads();
    int off = 0;
    for (int w2 = 0; w2 < w; ++w2) off += cnt[w2][mi];
    pos[t] = gbase[mi] + off + rank;
    __syncthreads();
    if (tid < E) {
      int tot = 0;
      for (int w2 = 0; w2 < 16; ++w2) tot += cnt[w2][tid];
      gbase[tid] += tot;
    }
    __syncthreads();
  }
  if (tid < E) kept[tid] = min(gbase[tid], cap);
}

// ---------------- scatter tokens to expert buffers (f32 -> bf16) ----------------
__global__ __launch_bounds__(64)
void scatter_kernel(const float* __restrict__ X, const int* __restrict__ idx,
                    const int* __restrict__ pos, int cap,
                    unsigned short* __restrict__ xbuf, int* __restrict__ tokmap,
                    float* __restrict__ mzero) {
  const int t = blockIdx.x;
  const int lane = threadIdx.x;
  const int p = pos[t];
  if (p < cap) {
    const size_t dst = ((size_t)idx[t] * cap + p) * D_;
    const float* xr = X + (size_t)t * D_;
#pragma unroll
    for (int i = 0; i < 4; ++i) {
      float4 v = *(const float4*)(xr + i * 256 + lane * 4);
      ushort4 o;
      o.x = f2bf(v.x); o.y = f2bf(v.y); o.z = f2bf(v.z); o.w = f2bf(v.w);
      *(ushort4*)(xbuf + dst + i * 256 + lane * 4) = o;
    }
    if (lane == 0) tokmap[(size_t)idx[t] * cap + p] = t;
  } else {
    float4 z = {0.f, 0.f, 0.f, 0.f};
    float* mr = mzero + (size_t)t * D_;
#pragma unroll
    for (int i = 0; i < 4; ++i) *(float4*)(mr + i * 256 + lane * 4) = z;
  }
}

// ---------------- weight transpose+convert: [K][N] f32 -> [N][K] bf16 ----------------
__global__ __launch_bounds__(256)
void wtrans_kernel(const float* __restrict__ src, unsigned short* __restrict__ dst,
                   int K, int N) {
  __shared__ float t[64][65];
  const int tid = threadIdx.x;
  const size_t eo = (size_t)blockIdx.z * K * N;
  const int k0 = blockIdx.y * 64, n0 = blockIdx.x * 64;
  const float* s = src + eo + (size_t)k0 * N + n0;
  unsigned short* d = dst + eo + (size_t)n0 * K + k0;
#pragma unroll
  for (int i = 0; i < 4; ++i) {
    int k = i * 16 + (tid >> 4);
    int n4 = (tid & 15) * 4;
    float4 v = *(const float4*)(s + (size_t)k * N + n4);
    t[k][n4] = v.x; t[k][n4 + 1] = v.y; t[k][n4 + 2] = v.z; t[k][n4 + 3] = v.w;
  }
  __syncthreads();
#pragma unroll
  for (int i = 0; i < 4; ++i) {
    int n = i * 16 + (tid >> 4);
    int k4 = (tid & 15) * 4;
    ushort4 o;
    o.x = f2bf(t[k4][n]);     o.y = f2bf(t[k4 + 1][n]);
    o.z = f2bf(t[k4 + 2][n]); o.w = f2bf(t[k4 + 3][n]);
    *(ushort4*)(d + (size_t)n * K + k4) = o;
  }
}

// ---------------- expert GEMM: C = A(bf16 [M][K]) * BT(bf16 [E][N][K])^T + bias ----
// MODE 0: Hout = relu(C) as bf16.   MODE 1: Mout[tok] = C * gate[tok] (gather).
template<int MODE>
__global__ __launch_bounds__(256)
void moe_gemm(const unsigned short* __restrict__ A,
              const unsigned short* __restrict__ BT,
              const float* __restrict__ bias, int K, int N, int cap, int nbcnt,
              const int* __restrict__ kept,
              unsigned short* __restrict__ Hout, float* __restrict__ Mout,
              const int* __restrict__ tokmap, const float* __restrict__ gate) {
  __shared__ char smem[16384];
  char* As = smem;          // [128][32] bf16, row-major, XOR-swizzled chunks
  char* Bs = smem + 8192;   // [128n][32k] bf16, same layout
  const int tid  = threadIdx.x;
  const int lane = tid & 63;
  const int wv   = tid >> 6;
  const int wr   = wv >> 1, wc = wv & 1;

  // XCD-chunk swizzle + group-of-4-mb for L2 locality
  const int nwg = gridDim.x;
  const int wg  = (blockIdx.x & 7) * (nwg >> 3) + (blockIdx.x >> 3);
  const int per_grp = nbcnt * 4;
  const int grp = wg / per_grp;
  const int rem = wg - grp * per_grp;
  const int mb  = grp * 4 + (rem & 3);
  const int nb  = rem >> 2;

  const int e  = (mb * 128) / cap;
  const int r0 = mb * 128 - e * cap;
  const int kept_e = kept[e];
  if (r0 >= kept_e) return;
  const unsigned short* Ab = A + (size_t)(mb * 128) * K;
  const unsigned short* Bb = BT + ((size_t)e * N + (size_t)nb * 128) * K;

  f32x4 acc[4][4];
#pragma unroll
  for (int m = 0; m < 4; ++m)
#pragma unroll
    for (int n = 0; n < 4; ++n) acc[m][n] = (f32x4){0.f, 0.f, 0.f, 0.f};

  const int srow = tid >> 2;          // row within 64-row half-tile
  const int scb  = (tid & 3) * 16;    // 16B chunk within 64B row

  for (int k0 = 0; k0 < K; k0 += 32) {
#pragma unroll
    for (int p = 0; p < 2; ++p) {
      const int row = p * 64 + srow;
      const int sw  = scb ^ ((row & 3) << 4);     // pre-swizzled source chunk
      const unsigned short* ga = Ab + (size_t)row * K + k0 + (sw >> 1);
      const unsigned short* gb = Bb + (size_t)row * K + k0 + (sw >> 1);
      char* la = As + (size_t)(p * 256 + (tid & ~63)) * 16;
      char* lb = Bs + (size_t)(p * 256 + (tid & ~63)) * 16;
      __builtin_amdgcn_global_load_lds((const __attribute__((address_space(1))) void*)ga,
                                       (__attribute__((address_space(3))) void*)la,
                                       16, 0, 0);
      __builtin_amdgcn_global_load_lds((const __attribute__((address_space(1))) void*)gb,
                                       (__attribute__((address_space(3))) void*)lb,
                                       16, 0, 0);
    }
    __syncthreads();

    bf16x8 af[4], bfr[4];
    const int g16 = (lane >> 4) * 16;
    const int r16 = lane & 15;
#pragma unroll
    for (int m = 0; m < 4; ++m) {
      const int row = wr * 64 + m * 16 + r16;
      af[m] = *(const bf16x8*)(As + row * 64 + (g16 ^ ((row & 3) << 4)));
      const int col = wc * 64 + m * 16 + r16;
      bfr[m] = *(const bf16x8*)(Bs + col * 64 + (g16 ^ ((col & 3) << 4)));
    }
#pragma unroll
    for (int m = 0; m < 4; ++m)
#pragma unroll
      for (int n = 0; n < 4; ++n)
        acc[m][n] = __builtin_amdgcn_mfma_f32_16x16x32_bf16(af[m], bfr[n], acc[m][n], 0, 0, 0);
    __syncthreads();
  }

  // epilogue
  const int r16 = lane & 15, rg = lane >> 4;
  float bv[4];
#pragma unroll
  for (int n = 0; n < 4; ++n)
    bv[n] = bias[(size_t)e * N + nb * 128 + wc * 64 + n * 16 + r16];

#pragma unroll
  for (int m = 0; m < 4; ++m) {
#pragma unroll
    for (int r = 0; r < 4; ++r) {
      const int lrow = wr * 64 + m * 16 + rg * 4 + r;
      if (MODE == 0) {
        unsigned short* orow = Hout + (size_t)(mb * 128 + lrow) * N + nb * 128;
#pragma unroll
        for (int n = 0; n < 4; ++n) {
          float v = acc[m][n][r] + bv[n];
          orow[wc * 64 + n * 16 + r16] = f2bf(fmaxf(v, 0.f));
        }
      } else {
        const int lr = r0 + lrow;
        if (lr < kept_e) {
          const int tok = tokmap[mb * 128 + lrow];
          const float gsc = gate[tok];
          float* orow = Mout + (size_t)tok * N + nb * 128;
#pragma unroll
          for (int n = 0; n < 4; ++n)
            orow[wc * 64 + n * 16 + r16] = (acc[m][n][r] + bv[n]) * gsc;
        }
      }
    }
  }
}

// ---------------- residual + mean over S ----------------
__global__ __launch_bounds__(256)
void reduce_kernel(const float* __restrict__ X, const float* __restrict__ M2,
                   float* __restrict__ sent) {
  const int c = blockIdx.x * 256 + threadIdx.x;   // 0..1023
  const int b = blockIdx.z;
  const int s0 = blockIdx.y * 128;
  float a = 0.f;
  size_t base = ((size_t)b * S_ + s0) * D_ + c;
  for (int s = 0; s < 128; ++s) a += X[base + (size_t)s * D_] + M2[base + (size_t)s * D_];
  atomicAdd(&sent[b * D_ + c], a * (1.0f / (float)S_));
}

// ---------------- logsumexp NLL loss ----------------
__global__ __launch_bounds__(64)
void loss_kernel(const float* __restrict__ sent, const int* __restrict__ y,
                 float* __restrict__ out) {
  const int lane = threadIdx.x;
  float total = 0.f;
  for (int b = 0; b < B_; ++b) {
    const float* s = sent + b * D_;
    float v[16];
    float mx = -1e30f;
#pragma unroll
    for (int i = 0; i < 16; ++i) { v[i] = s[lane + i * 64]; mx = fmaxf(mx, v[i]); }
#pragma unroll
    for (int sh = 32; sh >= 1; sh >>= 1) mx = fmaxf(mx, __shfl_xor(mx, sh, 64));
    float sm = 0.f;
#pragma unroll
    for (int i = 0; i < 16; ++i) sm += expf(v[i] - mx);
#pragma unroll
    for (int sh = 32; sh >= 1; sh >>= 1) sm += __shfl_xor(sm, sh, 64);
    total += logf(sm) + mx - s[y[b]];
  }
  if (lane == 0) out[0] = total * (1.0f / (float)B_);
}

extern "C" void kernel_launch(void* const* d_in, const int* in_sizes, int n_in,
                              void* d_out, int out_size, void* d_ws, size_t ws_size,
                              hipStream_t stream) {
  const float* x   = (const float*)d_in[0];
  const int*   y   = (const int*)d_in[1];
  const float* wg1 = (const float*)d_in[2];
  const float* w1a = (const float*)d_in[3];
  const float* b1a = (const float*)d_in[4];
  const float* w2a = (const float*)d_in[5];
  const float* b2a = (const float*)d_in[6];
  const float* wg2 = (const float*)d_in[7];
  const float* w1b = (const float*)d_in[8];
  const float* b1b = (const float*)d_in[9];
  const float* w2b = (const float*)d_in[10];
  const float* b2b = (const float*)d_in[11];
  float* out = (float*)d_out;
  (void)in_sizes; (void)n_in; (void)out_size; (void)ws_size;

  char* base = (char*)d_ws;
  size_t o = 0;
  auto alloc = [&](size_t bytes) { size_t r = o; o = (o + bytes + 255) & ~(size_t)255; return r; };
  int*   idx1    = (int*)  (base + alloc((size_t)T_ * 4));
  int*   pos1    = (int*)  (base + alloc((size_t)T_ * 4));
  float* gate1   = (float*)(base + alloc((size_t)T_ * 4));
  int*   idx2    = (int*)  (base + alloc((size_t)T_ * 4));
  int*   pos2    = (int*)  (base + alloc((size_t)T_ * 4));
  float* gate2   = (float*)(base + alloc((size_t)T_ * 4));
  int*   kept1   = (int*)  (base + alloc(64 * 4));
  int*   kept2   = (int*)  (base + alloc(64 * 4));
  int*   tokmap1 = (int*)  (base + alloc((size_t)EC_ * 4));
  int*   tokmap2 = (int*)  (base + alloc((size_t)EC_ * 4));
  float* sent    = (float*)(base + alloc((size_t)B_ * D_ * 4));
  float* m1      = (float*)(base + alloc((size_t)T_ * D_ * 4));   // layer-1 out, reused as layer-2 out
  unsigned short* xbuf = (unsigned short*)(base + alloc((size_t)EC_ * D_ * 2));    // 40 MB
  unsigned short* h    = (unsigned short*)(base + alloc((size_t)EC_ * DFF_ * 2));  // 160 MB
  unsigned short* wT   = (unsigned short*)(base + alloc((size_t)E2_ * D_ * DFF_ * 2)); // 128 MB, reused 4x

  hipMemsetAsync(sent, 0, (size_t)B_ * D_ * 4, stream);

  // ----- layer 1 (E=8, cap=2560) -----
  gate_kernel<E1_><<<T_ / 4, 256, 0, stream>>>(x, wg1, idx1, gate1);
  scan_kernel<<<1, 1024, 0, stream>>>(idx1, E1_, CAP1_, pos1, kept1);
  scatter_kernel<<<T_, 64, 0, stream>>>(x, idx1, pos1, CAP1_, xbuf, tokmap1, m1);
  wtrans_kernel<<<dim3(DFF_ / 64, D_ / 64, E1_), 256, 0, stream>>>(w1a, wT, D_, DFF_);
  moe_gemm<0><<<(DFF_ / 128) * (EC_ / 128), 256, 0, stream>>>(
      xbuf, wT, b1a, D_, DFF_, CAP1_, DFF_ / 128, kept1, h, nullptr, nullptr, nullptr);
  wtrans_kernel<<<dim3(D_ / 64, DFF_ / 64, E1_), 256, 0, stream>>>(w2a, wT, DFF_, D_);
  moe_gemm<1><<<(D_ / 128) * (EC_ / 128), 256, 0, stream>>>(
      h, wT, b2a, DFF_, D_, CAP1_, D_ / 128, kept1, nullptr, m1, tokmap1, gate1);

  // ----- layer 2 (E=16, cap=1280) -----
  gate_kernel<E2_><<<T_ / 4, 256, 0, stream>>>(m1, wg2, idx2, gate2);
  scan_kernel<<<1, 1024, 0, stream>>>(idx2, E2_, CAP2_, pos2, kept2);
  scatter_kernel<<<T_, 64, 0, stream>>>(m1, idx2, pos2, CAP2_, xbuf, tokmap2, m1);
  wtrans_kernel<<<dim3(DFF_ / 64, D_ / 64, E2_), 256, 0, stream>>>(w1b, wT, D_, DFF_);
  moe_gemm<0><<<(DFF_ / 128) * (EC_ / 128), 256, 0, stream>>>(
      xbuf, wT, b1b, D_, DFF_, CAP2_, DFF_ / 128, kept2, h, nullptr, nullptr, nullptr);
  wtrans_kernel<<<dim3(D_ / 64, DFF_ / 64, E2_), 256, 0, stream>>>(w2b, wT, DFF_, D_);
  moe_gemm<1><<<(D_ / 128) * (EC_ / 128), 256, 0, stream>>>(
      h, wT, b2b, DFF_, D_, CAP2_, D_ / 128, kept2, nullptr, m1, tokmap2, gate2);

  // ----- residual + mean + loss -----
  reduce_kernel<<<dim3(D_ / 256, S_ / 128, B_), 256, 0, stream>>>(x, m1, sent);
  loss_kernel<<<1, 64, 0, stream>>>(sent, y, out);
}

// Round 4
// 1381.239 us; speedup vs baseline: 1.1987x; 1.1165x over previous
//
#include <hip/hip_runtime.h>
#include <hip/hip_bf16.h>
#include <cstdint>
#include <cstddef>

#define B_    8
#define S_    2048
#define D_    1024
#define DFF_  4096
#define E1_   8
#define E2_   16
#define T_    (B_*S_)
#define CAP1_ 2560
#define CAP2_ 1280
#define EC_   20480   // E1_*CAP1_ == E2_*CAP2_ == padded expert-buffer rows

typedef __bf16 bf16x8 __attribute__((ext_vector_type(8)));
typedef float  f32x4  __attribute__((ext_vector_type(4)));

__device__ __forceinline__ unsigned short f2bf(float x) {
  return __builtin_bit_cast(unsigned short, (__bf16)x);
}

// ---------------- gating: logits = X @ WG, softmax-max + argmax ----------------
template<int E>
__global__ __launch_bounds__(256)
void gate_kernel(const float* __restrict__ X, const float* __restrict__ WG,
                 int* __restrict__ idxO, float* __restrict__ gateO) {
  const int lane = threadIdx.x & 63;
  const int wv   = threadIdx.x >> 6;
  const int t    = blockIdx.x * 4 + wv;
  const float* xr = X + (size_t)t * D_;
  float acc[E];
#pragma unroll
  for (int e = 0; e < E; ++e) acc[e] = 0.f;
#pragma unroll
  for (int i = 0; i < 4; ++i) {
    float4 xv = *(const float4*)(xr + i * 256 + lane * 4);
    int kb = i * 256 + lane * 4;
#pragma unroll
    for (int j = 0; j < 4; ++j) {
      float xs = (&xv.x)[j];
      const float* wr = WG + (size_t)(kb + j) * E;
#pragma unroll
      for (int e = 0; e < E; ++e) acc[e] += xs * wr[e];
    }
  }
#pragma unroll
  for (int e = 0; e < E; ++e) {
    float v = acc[e];
#pragma unroll
    for (int s = 32; s >= 1; s >>= 1) v += __shfl_xor(v, s, 64);
    acc[e] = v;
  }
  if (lane == 0) {
    float mx = acc[0]; int mi = 0;
#pragma unroll
    for (int e = 1; e < E; ++e) if (acc[e] > mx) { mx = acc[e]; mi = e; }
    float s = 0.f;
#pragma unroll
    for (int e = 0; e < E; ++e) s += expf(acc[e] - mx);
    idxO[t]  = mi;
    gateO[t] = 1.0f / s;   // max softmax prob
  }
}

// ---------------- order-preserving per-expert position scan ----------------
__global__ __launch_bounds__(1024)
void scan_kernel(const int* __restrict__ idx, int E, int cap,
                 int* __restrict__ pos, int* __restrict__ kept) {
  __shared__ int cnt[16][17];
  __shared__ int gbase[16];
  const int tid = threadIdx.x;
  const int w = tid >> 6, lane = tid & 63;
  if (tid < E) gbase[tid] = 0;
  __syncthreads();
  const unsigned long long lt = (lane == 63) ? 0xFFFFFFFFFFFFFFFFull >> 1
                                             : ((1ull << lane) - 1ull);
  for (int it = 0; it < T_ / 1024; ++it) {
    int t = it * 1024 + tid;
    int mi = idx[t];
    int rank = 0;
    for (int e = 0; e < E; ++e) {
      unsigned long long m = __ballot(mi == e);
      if (lane == 0) cnt[w][e] = __popcll(m);
      if (mi == e) rank = __popcll(m & lt);
    }
    __syncthreads();
    int off = 0;
    for (int w2 = 0; w2 < w; ++w2) off += cnt[w2][mi];
    pos[t] = gbase[mi] + off + rank;
    __syncthreads();
    if (tid < E) {
      int tot = 0;
      for (int w2 = 0; w2 < 16; ++w2) tot += cnt[w2][tid];
      gbase[tid] += tot;
    }
    __syncthreads();
  }
  if (tid < E) kept[tid] = min(gbase[tid], cap);
}

// ---------------- scatter tokens to expert buffers (f32 -> bf16) ----------------
__global__ __launch_bounds__(64)
void scatter_kernel(const float* __restrict__ X, const int* __restrict__ idx,
                    const int* __restrict__ pos, int cap,
                    unsigned short* __restrict__ xbuf, int* __restrict__ tokmap,
                    float* __restrict__ mzero) {
  const int t = blockIdx.x;
  const int lane = threadIdx.x;
  const int p = pos[t];
  if (p < cap) {
    const size_t dst = ((size_t)idx[t] * cap + p) * D_;
    const float* xr = X + (size_t)t * D_;
#pragma unroll
    for (int i = 0; i < 4; ++i) {
      float4 v = *(const float4*)(xr + i * 256 + lane * 4);
      ushort4 o;
      o.x = f2bf(v.x); o.y = f2bf(v.y); o.z = f2bf(v.z); o.w = f2bf(v.w);
      *(ushort4*)(xbuf + dst + i * 256 + lane * 4) = o;
    }
    if (lane == 0) tokmap[(size_t)idx[t] * cap + p] = t;
  } else {
    float4 z = {0.f, 0.f, 0.f, 0.f};
    float* mr = mzero + (size_t)t * D_;
#pragma unroll
    for (int i = 0; i < 4; ++i) *(float4*)(mr + i * 256 + lane * 4) = z;
  }
}

// ---------------- weight transpose+convert: [K][N] f32 -> [N][K] bf16 ----------------
__global__ __launch_bounds__(256)
void wtrans_kernel(const float* __restrict__ src, unsigned short* __restrict__ dst,
                   int K, int N) {
  __shared__ float t[64][65];
  const int tid = threadIdx.x;
  const size_t eo = (size_t)blockIdx.z * K * N;
  const int k0 = blockIdx.y * 64, n0 = blockIdx.x * 64;
  const float* s = src + eo + (size_t)k0 * N + n0;
  unsigned short* d = dst + eo + (size_t)n0 * K + k0;
#pragma unroll
  for (int i = 0; i < 4; ++i) {
    int k = i * 16 + (tid >> 4);
    int n4 = (tid & 15) * 4;
    float4 v = *(const float4*)(s + (size_t)k * N + n4);
    t[k][n4] = v.x; t[k][n4 + 1] = v.y; t[k][n4 + 2] = v.z; t[k][n4 + 3] = v.w;
  }
  __syncthreads();
#pragma unroll
  for (int i = 0; i < 4; ++i) {
    int n = i * 16 + (tid >> 4);
    int k4 = (tid & 15) * 4;
    ushort4 o;
    o.x = f2bf(t[k4][n]);     o.y = f2bf(t[k4 + 1][n]);
    o.z = f2bf(t[k4 + 2][n]); o.w = f2bf(t[k4 + 3][n]);
    *(ushort4*)(d + (size_t)n * K + k4) = o;
  }
}

// ---------------- expert GEMM: C = A(bf16 [M][K]) * BT(bf16 [E][N][K])^T + bias ----
// 128x128 tile, BK=64, double-buffered LDS, 2-phase prefetch, (row&7)<<4 swizzle.
// MODE 0: Hout = relu(C) as bf16.   MODE 1: Mout[tok] = C * gate[tok] (gather).
template<int MODE>
__global__ __launch_bounds__(256, 2)
void moe_gemm(const unsigned short* __restrict__ A,
              const unsigned short* __restrict__ BT,
              const float* __restrict__ bias, int K, int N, int cap, int nbcnt,
              const int* __restrict__ kept,
              unsigned short* __restrict__ Hout, float* __restrict__ Mout,
              const int* __restrict__ tokmap, const float* __restrict__ gate) {
  __shared__ char smem[65536];   // [2 bufs][A:16KB | B:16KB]
  const int tid  = threadIdx.x;
  const int lane = tid & 63;
  const int wv   = tid >> 6;
  const int wr   = wv >> 1, wc = wv & 1;

  // XCD-chunk swizzle + group-of-4-mb for L2 locality
  const int nwg = gridDim.x;
  const int wg  = (blockIdx.x & 7) * (nwg >> 3) + (blockIdx.x >> 3);
  const int per_grp = nbcnt * 4;
  const int grp = wg / per_grp;
  const int rem = wg - grp * per_grp;
  const int mb  = grp * 4 + (rem & 3);
  const int nb  = rem >> 2;

  const int e  = (mb * 128) / cap;
  const int r0 = mb * 128 - e * cap;
  const int kept_e = kept[e];
  if (r0 >= kept_e) return;
  const unsigned short* Ab = A + (size_t)(mb * 128) * K;
  const unsigned short* Bb = BT + ((size_t)e * N + (size_t)nb * 128) * K;

  f32x4 acc[4][4];
#pragma unroll
  for (int m = 0; m < 4; ++m)
#pragma unroll
    for (int n = 0; n < 4; ++n) acc[m][n] = (f32x4){0.f, 0.f, 0.f, 0.f};

  // stage one K-tile (128 rows x 64 k, A and B) into buf; source pre-swizzled
  auto stage = [&](int buf, int k0) {
#pragma unroll
    for (int j = 0; j < 4; ++j) {
      const int c   = j * 256 + tid;       // chunk id 0..1023
      const int row = c >> 3;              // 8 x 16B chunks per 128B row
      const int cc  = c & 7;
      const int scol = (cc ^ (row & 7)) << 3;   // source col in elements
      const unsigned short* ga = Ab + (size_t)row * K + k0 + scol;
      const unsigned short* gb = Bb + (size_t)row * K + k0 + scol;
      char* la = smem + buf * 32768 + (j * 256 + (tid & ~63)) * 16;
      char* lb = la + 16384;
      __builtin_amdgcn_global_load_lds((const __attribute__((address_space(1))) void*)ga,
                                       (__attribute__((address_space(3))) void*)la,
                                       16, 0, 0);
      __builtin_amdgcn_global_load_lds((const __attribute__((address_space(1))) void*)gb,
                                       (__attribute__((address_space(3))) void*)lb,
                                       16, 0, 0);
    }
  };

  const int NT = K >> 6;
  stage(0, 0);
  __syncthreads();   // drains vmcnt(0)+lgkmcnt(0) before barrier
  int cur = 0;

  const int g16 = (lane >> 4) * 16;
  const int r16 = lane & 15;

  for (int t = 0; t < NT; ++t) {
    if (t + 1 < NT) stage(cur ^ 1, (t + 1) << 6);   // issue next tile EARLY

    const char* As = smem + cur * 32768;
    const char* Bs = As + 16384;
    bf16x8 af[4][2], bfr[4][2];
#pragma unroll
    for (int m = 0; m < 4; ++m) {
      const int row = wr * 64 + m * 16 + r16;
      const int sw  = (row & 7) << 4;
#pragma unroll
      for (int ks = 0; ks < 2; ++ks)
        af[m][ks] = *(const bf16x8*)(As + row * 128 + ((ks * 64 + g16) ^ sw));
    }
#pragma unroll
    for (int n = 0; n < 4; ++n) {
      const int row = wc * 64 + n * 16 + r16;
      const int sw  = (row & 7) << 4;
#pragma unroll
      for (int ks = 0; ks < 2; ++ks)
        bfr[n][ks] = *(const bf16x8*)(Bs + row * 128 + ((ks * 64 + g16) ^ sw));
    }
    __builtin_amdgcn_s_setprio(1);
#pragma unroll
    for (int ks = 0; ks < 2; ++ks)
#pragma unroll
      for (int m = 0; m < 4; ++m)
#pragma unroll
        for (int n = 0; n < 4; ++n)
          acc[m][n] = __builtin_amdgcn_mfma_f32_16x16x32_bf16(af[m][ks], bfr[n][ks], acc[m][n], 0, 0, 0);
    __builtin_amdgcn_s_setprio(0);
    __syncthreads();   // drains the early-issued stage (latency hidden under compute)
    cur ^= 1;
  }

  // epilogue
  const int rg = lane >> 4;
  float bv[4];
#pragma unroll
  for (int n = 0; n < 4; ++n)
    bv[n] = bias[(size_t)e * N + nb * 128 + wc * 64 + n * 16 + r16];

#pragma unroll
  for (int m = 0; m < 4; ++m) {
#pragma unroll
    for (int r = 0; r < 4; ++r) {
      const int lrow = wr * 64 + m * 16 + rg * 4 + r;
      if (MODE == 0) {
        unsigned short* orow = Hout + (size_t)(mb * 128 + lrow) * N + nb * 128;
#pragma unroll
        for (int n = 0; n < 4; ++n) {
          float v = acc[m][n][r] + bv[n];
          orow[wc * 64 + n * 16 + r16] = f2bf(fmaxf(v, 0.f));
        }
      } else {
        const int lr = r0 + lrow;
        if (lr < kept_e) {
          const int tok = tokmap[mb * 128 + lrow];
          const float gsc = gate[tok];
          float* orow = Mout + (size_t)tok * N + nb * 128;
#pragma unroll
          for (int n = 0; n < 4; ++n)
            orow[wc * 64 + n * 16 + r16] = (acc[m][n][r] + bv[n]) * gsc;
        }
      }
    }
  }
}

// ---------------- residual + mean over S ----------------
__global__ __launch_bounds__(256)
void reduce_kernel(const float* __restrict__ X, const float* __restrict__ M2,
                   float* __restrict__ sent) {
  const int c = blockIdx.x * 256 + threadIdx.x;   // 0..1023
  const int b = blockIdx.z;
  const int s0 = blockIdx.y * 128;
  float a = 0.f;
  size_t base = ((size_t)b * S_ + s0) * D_ + c;
  for (int s = 0; s < 128; ++s) a += X[base + (size_t)s * D_] + M2[base + (size_t)s * D_];
  atomicAdd(&sent[b * D_ + c], a * (1.0f / (float)S_));
}

// ---------------- logsumexp NLL loss ----------------
__global__ __launch_bounds__(64)
void loss_kernel(const float* __restrict__ sent, const int* __restrict__ y,
                 float* __restrict__ out) {
  const int lane = threadIdx.x;
  float total = 0.f;
  for (int b = 0; b < B_; ++b) {
    const float* s = sent + b * D_;
    float v[16];
    float mx = -1e30f;
#pragma unroll
    for (int i = 0; i < 16; ++i) { v[i] = s[lane + i * 64]; mx = fmaxf(mx, v[i]); }
#pragma unroll
    for (int sh = 32; sh >= 1; sh >>= 1) mx = fmaxf(mx, __shfl_xor(mx, sh, 64));
    float sm = 0.f;
#pragma unroll
    for (int i = 0; i < 16; ++i) sm += expf(v[i] - mx);
#pragma unroll
    for (int sh = 32; sh >= 1; sh >>= 1) sm += __shfl_xor(sm, sh, 64);
    total += logf(sm) + mx - s[y[b]];
  }
  if (lane == 0) out[0] = total * (1.0f / (float)B_);
}

extern "C" void kernel_launch(void* const* d_in, const int* in_sizes, int n_in,
                              void* d_out, int out_size, void* d_ws, size_t ws_size,
                              hipStream_t stream) {
  const float* x   = (const float*)d_in[0];
  const int*   y   = (const int*)d_in[1];
  const float* wg1 = (const float*)d_in[2];
  const float* w1a = (const float*)d_in[3];
  const float* b1a = (const float*)d_in[4];
  const float* w2a = (const float*)d_in[5];
  const float* b2a = (const float*)d_in[6];
  const float* wg2 = (const float*)d_in[7];
  const float* w1b = (const float*)d_in[8];
  const float* b1b = (const float*)d_in[9];
  const float* w2b = (const float*)d_in[10];
  const float* b2b = (const float*)d_in[11];
  float* out = (float*)d_out;
  (void)in_sizes; (void)n_in; (void)out_size; (void)ws_size;

  char* base = (char*)d_ws;
  size_t o = 0;
  auto alloc = [&](size_t bytes) { size_t r = o; o = (o + bytes + 255) & ~(size_t)255; return r; };
  int*   idx1    = (int*)  (base + alloc((size_t)T_ * 4));
  int*   pos1    = (int*)  (base + alloc((size_t)T_ * 4));
  float* gate1   = (float*)(base + alloc((size_t)T_ * 4));
  int*   idx2    = (int*)  (base + alloc((size_t)T_ * 4));
  int*   pos2    = (int*)  (base + alloc((size_t)T_ * 4));
  float* gate2   = (float*)(base + alloc((size_t)T_ * 4));
  int*   kept1   = (int*)  (base + alloc(64 * 4));
  int*   kept2   = (int*)  (base + alloc(64 * 4));
  int*   tokmap1 = (int*)  (base + alloc((size_t)EC_ * 4));
  int*   tokmap2 = (int*)  (base + alloc((size_t)EC_ * 4));
  float* sent    = (float*)(base + alloc((size_t)B_ * D_ * 4));
  float* m1      = (float*)(base + alloc((size_t)T_ * D_ * 4));   // layer-1 out, reused as layer-2 out
  unsigned short* xbuf = (unsigned short*)(base + alloc((size_t)EC_ * D_ * 2));    // 40 MB
  unsigned short* h    = (unsigned short*)(base + alloc((size_t)EC_ * DFF_ * 2));  // 160 MB
  unsigned short* wT   = (unsigned short*)(base + alloc((size_t)E2_ * D_ * DFF_ * 2)); // 128 MB, reused 4x

  hipMemsetAsync(sent, 0, (size_t)B_ * D_ * 4, stream);

  // ----- layer 1 (E=8, cap=2560) -----
  gate_kernel<E1_><<<T_ / 4, 256, 0, stream>>>(x, wg1, idx1, gate1);
  scan_kernel<<<1, 1024, 0, stream>>>(idx1, E1_, CAP1_, pos1, kept1);
  scatter_kernel<<<T_, 64, 0, stream>>>(x, idx1, pos1, CAP1_, xbuf, tokmap1, m1);
  wtrans_kernel<<<dim3(DFF_ / 64, D_ / 64, E1_), 256, 0, stream>>>(w1a, wT, D_, DFF_);
  moe_gemm<0><<<(DFF_ / 128) * (EC_ / 128), 256, 0, stream>>>(
      xbuf, wT, b1a, D_, DFF_, CAP1_, DFF_ / 128, kept1, h, nullptr, nullptr, nullptr);
  wtrans_kernel<<<dim3(D_ / 64, DFF_ / 64, E1_), 256, 0, stream>>>(w2a, wT, DFF_, D_);
  moe_gemm<1><<<(D_ / 128) * (EC_ / 128), 256, 0, stream>>>(
      h, wT, b2a, DFF_, D_, CAP1_, D_ / 128, kept1, nullptr, m1, tokmap1, gate1);

  // ----- layer 2 (E=16, cap=1280) -----
  gate_kernel<E2_><<<T_ / 4, 256, 0, stream>>>(m1, wg2, idx2, gate2);
  scan_kernel<<<1, 1024, 0, stream>>>(idx2, E2_, CAP2_, pos2, kept2);
  scatter_kernel<<<T_, 64, 0, stream>>>(m1, idx2, pos2, CAP2_, xbuf, tokmap2, m1);
  wtrans_kernel<<<dim3(DFF_ / 64, D_ / 64, E2_), 256, 0, stream>>>(w1b, wT, D_, DFF_);
  moe_gemm<0><<<(DFF_ / 128) * (EC_ / 128), 256, 0, stream>>>(
      xbuf, wT, b1b, D_, DFF_, CAP2_, DFF_ / 128, kept2, h, nullptr, nullptr, nullptr);
  wtrans_kernel<<<dim3(D_ / 64, DFF_ / 64, E2_), 256, 0, stream>>>(w2b, wT, DFF_, D_);
  moe_gemm<1><<<(D_ / 128) * (EC_ / 128), 256, 0, stream>>>(
      h, wT, b2b, DFF_, D_, CAP2_, D_ / 128, kept2, nullptr, m1, tokmap2, gate2);

  // ----- residual + mean + loss -----
  reduce_kernel<<<dim3(D_ / 256, S_ / 128, B_), 256, 0, stream>>>(x, m1, sent);
  loss_kernel<<<1, 64, 0, stream>>>(sent, y, out);
}

// Round 5
// 1292.854 us; speedup vs baseline: 1.2806x; 1.0684x over previous
//
#include <hip/hip_runtime.h>
#include <hip/hip_bf16.h>
#include <cstdint>
#include <cstddef>

#define B_    8
#define S_    2048
#define D_    1024
#define DFF_  4096
#define E1_   8
#define E2_   16
#define T_    (B_*S_)
#define CAP1_ 2560
#define CAP2_ 1280
#define EC_   20480   // E1_*CAP1_ == E2_*CAP2_ == padded expert-buffer rows

typedef __bf16 bf16x8 __attribute__((ext_vector_type(8)));
typedef float  f32x4  __attribute__((ext_vector_type(4)));

__device__ __forceinline__ unsigned short f2bf(float x) {
  return __builtin_bit_cast(unsigned short, (__bf16)x);
}

// ---------------- gating: logits = X @ WG, softmax-max + argmax ----------------
template<int E>
__global__ __launch_bounds__(256)
void gate_kernel(const float* __restrict__ X, const float* __restrict__ WG,
                 int* __restrict__ idxO, float* __restrict__ gateO) {
  const int lane = threadIdx.x & 63;
  const int wv   = threadIdx.x >> 6;
  const int t    = blockIdx.x * 4 + wv;
  const float* xr = X + (size_t)t * D_;
  float acc[E];
#pragma unroll
  for (int e = 0; e < E; ++e) acc[e] = 0.f;
#pragma unroll
  for (int i = 0; i < 4; ++i) {
    float4 xv = *(const float4*)(xr + i * 256 + lane * 4);
    int kb = i * 256 + lane * 4;
#pragma unroll
    for (int j = 0; j < 4; ++j) {
      float xs = (&xv.x)[j];
      const float* wr = WG + (size_t)(kb + j) * E;
#pragma unroll
      for (int e = 0; e < E; ++e) acc[e] += xs * wr[e];
    }
  }
#pragma unroll
  for (int e = 0; e < E; ++e) {
    float v = acc[e];
#pragma unroll
    for (int s = 32; s >= 1; s >>= 1) v += __shfl_xor(v, s, 64);
    acc[e] = v;
  }
  if (lane == 0) {
    float mx = acc[0]; int mi = 0;
#pragma unroll
    for (int e = 1; e < E; ++e) if (acc[e] > mx) { mx = acc[e]; mi = e; }
    float s = 0.f;
#pragma unroll
    for (int e = 0; e < E; ++e) s += expf(acc[e] - mx);
    idxO[t]  = mi;
    gateO[t] = 1.0f / s;   // max softmax prob
  }
}

// ---------------- order-preserving per-expert position scan ----------------
__global__ __launch_bounds__(1024)
void scan_kernel(const int* __restrict__ idx, int E, int cap,
                 int* __restrict__ pos, int* __restrict__ kept) {
  __shared__ int cnt[16][17];
  __shared__ int gbase[16];
  const int tid = threadIdx.x;
  const int w = tid >> 6, lane = tid & 63;
  if (tid < E) gbase[tid] = 0;
  __syncthreads();
  const unsigned long long lt = (lane == 63) ? 0xFFFFFFFFFFFFFFFFull >> 1
                                             : ((1ull << lane) - 1ull);
  for (int it = 0; it < T_ / 1024; ++it) {
    int t = it * 1024 + tid;
    int mi = idx[t];
    int rank = 0;
    for (int e = 0; e < E; ++e) {
      unsigned long long m = __ballot(mi == e);
      if (lane == 0) cnt[w][e] = __popcll(m);
      if (mi == e) rank = __popcll(m & lt);
    }
    __syncthreads();
    int off = 0;
    for (int w2 = 0; w2 < w; ++w2) off += cnt[w2][mi];
    pos[t] = gbase[mi] + off + rank;
    __syncthreads();
    if (tid < E) {
      int tot = 0;
      for (int w2 = 0; w2 < 16; ++w2) tot += cnt[w2][tid];
      gbase[tid] += tot;
    }
    __syncthreads();
  }
  if (tid < E) kept[tid] = min(gbase[tid], cap);
}

// ---------------- scatter tokens to expert buffers (f32 -> bf16) ----------------
__global__ __launch_bounds__(64)
void scatter_kernel(const float* __restrict__ X, const int* __restrict__ idx,
                    const int* __restrict__ pos, int cap,
                    unsigned short* __restrict__ xbuf, int* __restrict__ tokmap,
                    float* __restrict__ mzero) {
  const int t = blockIdx.x;
  const int lane = threadIdx.x;
  const int p = pos[t];
  if (p < cap) {
    const size_t dst = ((size_t)idx[t] * cap + p) * D_;
    const float* xr = X + (size_t)t * D_;
#pragma unroll
    for (int i = 0; i < 4; ++i) {
      float4 v = *(const float4*)(xr + i * 256 + lane * 4);
      ushort4 o;
      o.x = f2bf(v.x); o.y = f2bf(v.y); o.z = f2bf(v.z); o.w = f2bf(v.w);
      *(ushort4*)(xbuf + dst + i * 256 + lane * 4) = o;
    }
    if (lane == 0) tokmap[(size_t)idx[t] * cap + p] = t;
  } else {
    float4 z = {0.f, 0.f, 0.f, 0.f};
    float* mr = mzero + (size_t)t * D_;
#pragma unroll
    for (int i = 0; i < 4; ++i) *(float4*)(mr + i * 256 + lane * 4) = z;
  }
}

// ---------------- weight transpose+convert: [K][N] f32 -> [N][K] bf16 ----------------
__global__ __launch_bounds__(256)
void wtrans_kernel(const float* __restrict__ src, unsigned short* __restrict__ dst,
                   int K, int N) {
  __shared__ float t[64][65];
  const int tid = threadIdx.x;
  const size_t eo = (size_t)blockIdx.z * K * N;
  const int k0 = blockIdx.y * 64, n0 = blockIdx.x * 64;
  const float* s = src + eo + (size_t)k0 * N + n0;
  unsigned short* d = dst + eo + (size_t)n0 * K + k0;
#pragma unroll
  for (int i = 0; i < 4; ++i) {
    int k = i * 16 + (tid >> 4);
    int n4 = (tid & 15) * 4;
    float4 v = *(const float4*)(s + (size_t)k * N + n4);
    t[k][n4] = v.x; t[k][n4 + 1] = v.y; t[k][n4 + 2] = v.z; t[k][n4 + 3] = v.w;
  }
  __syncthreads();
#pragma unroll
  for (int i = 0; i < 4; ++i) {
    int n = i * 16 + (tid >> 4);
    int k4 = (tid & 15) * 4;
    ushort4 o;
    o.x = f2bf(t[k4][n]);     o.y = f2bf(t[k4 + 1][n]);
    o.z = f2bf(t[k4 + 2][n]); o.w = f2bf(t[k4 + 3][n]);
    *(ushort4*)(d + (size_t)n * K + k4) = o;
  }
}

// ---------------- expert GEMM: 256x256 tile, BK=64, 8-phase counted-vmcnt ------
// A bf16 [M][K], BT bf16 [E][N][K]. 512 thr = 8 waves (2M x 4N), per-wave 128x64.
// LDS 128KB: 2 bufs x {A0,A1,B0,B1} half-slots of 16KB ([128 rows][64 k] bf16,
// chunk ^= (row&7)<<4 swizzle, gload_lds linear dest + pre-swizzled source).
// MODE 0: Hout = relu(C) bf16.  MODE 1: Mout[tok] = C * gate[tok] (gather).
#define STG(BASEPTR, H, KT, SLOT) do {                                          \
    const unsigned short* _s = (BASEPTR) + (size_t)((H) * 128) * K + (KT) + st_off; \
    __builtin_amdgcn_global_load_lds((const __attribute__((address_space(1))) void*)_s, \
        (__attribute__((address_space(3))) void*)(smem + (SLOT) + dst0), 16, 0, 0);   \
    __builtin_amdgcn_global_load_lds((const __attribute__((address_space(1))) void*)(_s + (size_t)64 * K), \
        (__attribute__((address_space(3))) void*)(smem + (SLOT) + 8192 + dst0), 16, 0, 0); \
  } while (0)

#define RDA(BUF, MH) do { _Pragma("unroll")                                     \
    for (int m_ = 0; m_ < 4; ++m_) {                                            \
      const char* _p = smem + (BUF) * 65536 + aslot + ((MH) * 4 + m_) * 2048;   \
      af[m_][0] = *(const bf16x8*)(_p + va);                                    \
      af[m_][1] = *(const bf16x8*)(_p + (va ^ 64)); } } while (0)

#define RDB(BUF, NH) do { _Pragma("unroll")                                     \
    for (int j_ = 0; j_ < 2; ++j_) {                                            \
      const char* _p = smem + (BUF) * 65536 + bslot + ((NH) * 2 + j_) * 2048;   \
      bf[(NH) * 2 + j_][0] = *(const bf16x8*)(_p + vb);                         \
      bf[(NH) * 2 + j_][1] = *(const bf16x8*)(_p + (vb ^ 64)); } } while (0)

#define QUAD(MH, NH) do {                                                       \
    __builtin_amdgcn_s_setprio(1);                                              \
    _Pragma("unroll") for (int m_ = 0; m_ < 4; ++m_)                            \
    _Pragma("unroll") for (int j_ = 0; j_ < 2; ++j_)                            \
    _Pragma("unroll") for (int k_ = 0; k_ < 2; ++k_)                            \
      acc[(MH) * 4 + m_][(NH) * 2 + j_] = __builtin_amdgcn_mfma_f32_16x16x32_bf16( \
          af[m_][k_], bf[(NH) * 2 + j_][k_], acc[(MH) * 4 + m_][(NH) * 2 + j_], 0, 0, 0); \
    __builtin_amdgcn_s_setprio(0);                                              \
  } while (0)

#define LGKM0 do { asm volatile("s_waitcnt lgkmcnt(0)" ::: "memory");           \
                   __builtin_amdgcn_sched_barrier(0); } while (0)
#define BAR   __builtin_amdgcn_s_barrier()
#define VM4   asm volatile("s_waitcnt vmcnt(4)" ::: "memory")
#define VM0   asm volatile("s_waitcnt vmcnt(0)" ::: "memory")

template<int MODE>
__global__ __launch_bounds__(512, 2)
void moe_gemm(const unsigned short* __restrict__ A,
              const unsigned short* __restrict__ BT,
              const float* __restrict__ bias, int K, int N, int cap, int nbcnt,
              const int* __restrict__ kept,
              unsigned short* __restrict__ Hout, float* __restrict__ Mout,
              const int* __restrict__ tokmap, const float* __restrict__ gate) {
  __shared__ char smem[131072];
  const int tid  = threadIdx.x;
  const int lane = tid & 63;
  const int wv   = tid >> 6;      // 0..7
  const int wr   = wv >> 2;       // 0..1 (M half)
  const int wc   = wv & 3;        // 0..3 (N quarter)

  // XCD-chunk swizzle + group-of-4-mb for L2 locality
  const int nwg = gridDim.x;
  const int wg  = (blockIdx.x & 7) * (nwg >> 3) + (blockIdx.x >> 3);
  const int per_grp = nbcnt * 4;
  const int grp = wg / per_grp;
  const int rem = wg - grp * per_grp;
  const int mb  = grp * 4 + (rem & 3);
  const int nb  = rem >> 2;

  const int e  = (mb * 256) / cap;
  const int r0 = mb * 256 - e * cap;
  const int kept_e = kept[e];
  if (r0 >= kept_e) return;
  const unsigned short* Ab = A + (size_t)(mb * 256) * K;
  const unsigned short* Bb = BT + ((size_t)e * N + (size_t)nb * 256) * K;

  f32x4 acc[8][4];
#pragma unroll
  for (int m = 0; m < 8; ++m)
#pragma unroll
    for (int n = 0; n < 4; ++n) acc[m][n] = (f32x4){0.f, 0.f, 0.f, 0.f};

  // staging addressing: chunk c = l*512+tid; row = l*64 + (tid>>3); cc = tid&7
  const int scol   = ((tid & 7) ^ ((tid >> 3) & 7)) * 8;  // pre-swizzled src col
  const size_t st_off = (size_t)(tid >> 3) * K + scol;
  const int dst0   = tid * 16;

  // fragment read addressing
  const int r16 = lane & 15;
  const int g16 = (lane >> 4) * 16;
  const int swz = (r16 & 7) * 16;
  const int va  = r16 * 128 + (g16 ^ swz);
  const int vb  = (wc & 1) * 8192 + va;
  const int aslot = wr * 16384;
  const int bslot = 32768 + (wc >> 1) * 16384;
  bf16x8 af[4][2], bf[4][2];

  // prologue: tile0 -> buf0 {A0,A1,B0,B1}; tile1 {B0,B1} -> buf1
  STG(Ab, 0, 0, 0);
  STG(Ab, 1, 0, 16384);
  STG(Bb, 0, 0, 32768);
  STG(Bb, 1, 0, 49152);
  STG(Bb, 0, 64, 65536 + 32768);
  STG(Bb, 1, 64, 65536 + 49152);
  VM4; BAR;

  const int NI = K >> 7;   // 2 K-tiles (2x64) per iteration
  for (int i = 0; i < NI; ++i) {
    const bool last = (i == NI - 1);
    const int kt1 = (2 * i + 1) << 6;
    const int kt2 = (2 * i + 2) << 6;
    const int kt3 = (2 * i + 3) << 6;

    // ph1: compute buf0 quad(mh0,nh0); stage buf1.A0 <- tile(2i+1)
    RDA(0, 0); RDB(0, 0);
    STG(Ab, 0, kt1, 65536);
    BAR; LGKM0; QUAD(0, 0); BAR;
    // ph2
    RDB(0, 1);
    STG(Ab, 1, kt1, 65536 + 16384);
    BAR; LGKM0; QUAD(0, 1); BAR;
    // ph3
    RDA(0, 1);
    if (!last) STG(Bb, 0, kt2, 32768);
    BAR; LGKM0; QUAD(1, 1); BAR;
    // ph4 (checkpoint)
    if (!last) { STG(Bb, 1, kt2, 49152); VM4; } else { VM0; }
    BAR; __builtin_amdgcn_sched_barrier(0);
    QUAD(1, 0); BAR;
    // ph5: compute buf1 quad(mh0,nh0); stage buf0.A0 <- tile(2i+2)
    RDA(1, 0); RDB(1, 0);
    if (!last) STG(Ab, 0, kt2, 0);
    BAR; LGKM0; QUAD(0, 0); BAR;
    // ph6
    RDB(1, 1);
    if (!last) STG(Ab, 1, kt2, 16384);
    BAR; LGKM0; QUAD(0, 1); BAR;
    // ph7
    RDA(1, 1);
    if (!last) STG(Bb, 0, kt3, 65536 + 32768);
    BAR; LGKM0; QUAD(1, 1); BAR;
    // ph8 (checkpoint)
    if (!last) { STG(Bb, 1, kt3, 65536 + 49152); VM4; }
    BAR; __builtin_amdgcn_sched_barrier(0);
    QUAD(1, 0); BAR;
  }

  // epilogue
  const int rg = lane >> 4;
  float bv[4];
#pragma unroll
  for (int n = 0; n < 4; ++n)
    bv[n] = bias[(size_t)e * N + nb * 256 + wc * 64 + n * 16 + r16];

#pragma unroll
  for (int m = 0; m < 8; ++m) {
#pragma unroll
    for (int r = 0; r < 4; ++r) {
      const int lrow = wr * 128 + m * 16 + rg * 4 + r;
      if (MODE == 0) {
        unsigned short* orow = Hout + (size_t)(mb * 256 + lrow) * N + nb * 256;
#pragma unroll
        for (int n = 0; n < 4; ++n) {
          float v = acc[m][n][r] + bv[n];
          orow[wc * 64 + n * 16 + r16] = f2bf(fmaxf(v, 0.f));
        }
      } else {
        const int lr = r0 + lrow;
        if (lr < kept_e) {
          const int tok = tokmap[mb * 256 + lrow];
          const float gsc = gate[tok];
          float* orow = Mout + (size_t)tok * N + nb * 256;
#pragma unroll
          for (int n = 0; n < 4; ++n)
            orow[wc * 64 + n * 16 + r16] = (acc[m][n][r] + bv[n]) * gsc;
        }
      }
    }
  }
}

// ---------------- residual + mean over S ----------------
__global__ __launch_bounds__(256)
void reduce_kernel(const float* __restrict__ X, const float* __restrict__ M2,
                   float* __restrict__ sent) {
  const int c = blockIdx.x * 256 + threadIdx.x;   // 0..1023
  const int b = blockIdx.z;
  const int s0 = blockIdx.y * 128;
  float a = 0.f;
  size_t base = ((size_t)b * S_ + s0) * D_ + c;
  for (int s = 0; s < 128; ++s) a += X[base + (size_t)s * D_] + M2[base + (size_t)s * D_];
  atomicAdd(&sent[b * D_ + c], a * (1.0f / (float)S_));
}

// ---------------- logsumexp NLL loss ----------------
__global__ __launch_bounds__(64)
void loss_kernel(const float* __restrict__ sent, const int* __restrict__ y,
                 float* __restrict__ out) {
  const int lane = threadIdx.x;
  float total = 0.f;
  for (int b = 0; b < B_; ++b) {
    const float* s = sent + b * D_;
    float v[16];
    float mx = -1e30f;
#pragma unroll
    for (int i = 0; i < 16; ++i) { v[i] = s[lane + i * 64]; mx = fmaxf(mx, v[i]); }
#pragma unroll
    for (int sh = 32; sh >= 1; sh >>= 1) mx = fmaxf(mx, __shfl_xor(mx, sh, 64));
    float sm = 0.f;
#pragma unroll
    for (int i = 0; i < 16; ++i) sm += expf(v[i] - mx);
#pragma unroll
    for (int sh = 32; sh >= 1; sh >>= 1) sm += __shfl_xor(sm, sh, 64);
    total += logf(sm) + mx - s[y[b]];
  }
  if (lane == 0) out[0] = total * (1.0f / (float)B_);
}

extern "C" void kernel_launch(void* const* d_in, const int* in_sizes, int n_in,
                              void* d_out, int out_size, void* d_ws, size_t ws_size,
                              hipStream_t stream) {
  const float* x   = (const float*)d_in[0];
  const int*   y   = (const int*)d_in[1];
  const float* wg1 = (const float*)d_in[2];
  const float* w1a = (const float*)d_in[3];
  const float* b1a = (const float*)d_in[4];
  const float* w2a = (const float*)d_in[5];
  const float* b2a = (const float*)d_in[6];
  const float* wg2 = (const float*)d_in[7];
  const float* w1b = (const float*)d_in[8];
  const float* b1b = (const float*)d_in[9];
  const float* w2b = (const float*)d_in[10];
  const float* b2b = (const float*)d_in[11];
  float* out = (float*)d_out;
  (void)in_sizes; (void)n_in; (void)out_size; (void)ws_size;

  char* base = (char*)d_ws;
  size_t o = 0;
  auto alloc = [&](size_t bytes) { size_t r = o; o = (o + bytes + 255) & ~(size_t)255; return r; };
  int*   idx1    = (int*)  (base + alloc((size_t)T_ * 4));
  int*   pos1    = (int*)  (base + alloc((size_t)T_ * 4));
  float* gate1   = (float*)(base + alloc((size_t)T_ * 4));
  int*   idx2    = (int*)  (base + alloc((size_t)T_ * 4));
  int*   pos2    = (int*)  (base + alloc((size_t)T_ * 4));
  float* gate2   = (float*)(base + alloc((size_t)T_ * 4));
  int*   kept1   = (int*)  (base + alloc(64 * 4));
  int*   kept2   = (int*)  (base + alloc(64 * 4));
  int*   tokmap1 = (int*)  (base + alloc((size_t)EC_ * 4));
  int*   tokmap2 = (int*)  (base + alloc((size_t)EC_ * 4));
  float* sent    = (float*)(base + alloc((size_t)B_ * D_ * 4));
  float* m1      = (float*)(base + alloc((size_t)T_ * D_ * 4));   // layer-1 out, reused as layer-2 out
  unsigned short* xbuf = (unsigned short*)(base + alloc((size_t)EC_ * D_ * 2));    // 40 MB
  unsigned short* h    = (unsigned short*)(base + alloc((size_t)EC_ * DFF_ * 2));  // 160 MB
  unsigned short* wT   = (unsigned short*)(base + alloc((size_t)E2_ * D_ * DFF_ * 2)); // 128 MB, reused 4x

  hipMemsetAsync(sent, 0, (size_t)B_ * D_ * 4, stream);

  // ----- layer 1 (E=8, cap=2560) -----
  gate_kernel<E1_><<<T_ / 4, 256, 0, stream>>>(x, wg1, idx1, gate1);
  scan_kernel<<<1, 1024, 0, stream>>>(idx1, E1_, CAP1_, pos1, kept1);
  scatter_kernel<<<T_, 64, 0, stream>>>(x, idx1, pos1, CAP1_, xbuf, tokmap1, m1);
  wtrans_kernel<<<dim3(DFF_ / 64, D_ / 64, E1_), 256, 0, stream>>>(w1a, wT, D_, DFF_);
  moe_gemm<0><<<(DFF_ / 256) * (EC_ / 256), 512, 0, stream>>>(
      xbuf, wT, b1a, D_, DFF_, CAP1_, DFF_ / 256, kept1, h, nullptr, nullptr, nullptr);
  wtrans_kernel<<<dim3(D_ / 64, DFF_ / 64, E1_), 256, 0, stream>>>(w2a, wT, DFF_, D_);
  moe_gemm<1><<<(D_ / 256) * (EC_ / 256), 512, 0, stream>>>(
      h, wT, b2a, DFF_, D_, CAP1_, D_ / 256, kept1, nullptr, m1, tokmap1, gate1);

  // ----- layer 2 (E=16, cap=1280) -----
  gate_kernel<E2_><<<T_ / 4, 256, 0, stream>>>(m1, wg2, idx2, gate2);
  scan_kernel<<<1, 1024, 0, stream>>>(idx2, E2_, CAP2_, pos2, kept2);
  scatter_kernel<<<T_, 64, 0, stream>>>(m1, idx2, pos2, CAP2_, xbuf, tokmap2, m1);
  wtrans_kernel<<<dim3(DFF_ / 64, D_ / 64, E2_), 256, 0, stream>>>(w1b, wT, D_, DFF_);
  moe_gemm<0><<<(DFF_ / 256) * (EC_ / 256), 512, 0, stream>>>(
      xbuf, wT, b1b, D_, DFF_, CAP2_, DFF_ / 256, kept2, h, nullptr, nullptr, nullptr);
  wtrans_kernel<<<dim3(D_ / 64, DFF_ / 64, E2_), 256, 0, stream>>>(w2b, wT, DFF_, D_);
  moe_gemm<1><<<(D_ / 256) * (EC_ / 256), 512, 0, stream>>>(
      h, wT, b2b, DFF_, D_, CAP2_, D_ / 256, kept2, nullptr, m1, tokmap2, gate2);

  // ----- residual + mean + loss -----
  reduce_kernel<<<dim3(D_ / 256, S_ / 128, B_), 256, 0, stream>>>(x, m1, sent);
  loss_kernel<<<1, 64, 0, stream>>>(sent, y, out);
}